// Round 1
// baseline (689.507 us; speedup 1.0000x reference)
//
#include <hip/hip_runtime.h>
#include <hip/hip_bf16.h>

#define IN_DIM 128
#define OUT_DIM 128
#define EDGE_DIM 64

typedef __attribute__((ext_vector_type(8))) short short8;
typedef __attribute__((ext_vector_type(4))) float f32x4;

static __device__ __forceinline__ unsigned short f2bf(float f) {
    unsigned u = __builtin_bit_cast(unsigned, f);
    u += 0x7fffu + ((u >> 16) & 1u);   // round-to-nearest-even
    return (unsigned short)(u >> 16);
}
static __device__ __forceinline__ float bf2f(unsigned short s) {
    unsigned u = ((unsigned)s) << 16;
    return __builtin_bit_cast(float, u);
}

// ---- kernel 0a: h (fp32) -> bf16 ----
__global__ void cvt_h_kernel(const float* __restrict__ src,
                             unsigned short* __restrict__ dst, int n4) {
    int i = blockIdx.x * 256 + threadIdx.x;
    if (i >= n4) return;
    float4 v = ((const float4*)src)[i];
    ushort4 o;
    o.x = f2bf(v.x); o.y = f2bf(v.y); o.z = f2bf(v.z); o.w = f2bf(v.w);
    ((ushort4*)dst)[i] = o;
}

// ---- kernel 0b: W_e / W_hu / W_hw -> bf16 ----
__global__ void cvt_w_kernel(const float* __restrict__ We,
                             const float* __restrict__ Whu,
                             const float* __restrict__ Whw,
                             unsigned short* __restrict__ oWe,
                             unsigned short* __restrict__ oWhu,
                             unsigned short* __restrict__ oWhw) {
    int i = blockIdx.x * 256 + threadIdx.x;   // 0..40959
    if (i < 8192)        oWe[i]          = f2bf(We[i]);
    else if (i < 24576)  oWhu[i - 8192]  = f2bf(Whu[i - 8192]);
    else if (i < 40960)  oWhw[i - 24576] = f2bf(Whw[i - 24576]);
}

// ---- kernel 1: hu = h@W_huT, hw = h@W_hwT (bf16 MFMA, LDS-free) ----
// grid = (ceil(N/64), 2), block = 256 (4 waves, each wave 16 rows x 128 cols)
__global__ __launch_bounds__(256) void proj_kernel(
    const unsigned short* __restrict__ hbf,   // [N][128] bf16
    const unsigned short* __restrict__ Wa,    // [128][128] bf16 (W_hu)
    const unsigned short* __restrict__ Wb,    // [128][128] bf16 (W_hw)
    unsigned short* __restrict__ hu,          // [N][128] bf16
    unsigned short* __restrict__ hw,
    int N) {
    const unsigned short* W = (blockIdx.y == 0) ? Wa : Wb;
    unsigned short*       P = (blockIdx.y == 0) ? hu : hw;
    int tid = threadIdx.x;
    int w = tid >> 6, l = tid & 63;
    int lr = l >> 4, lc = l & 15;

    int rowA = blockIdx.x * 64 + w * 16 + lc;
    if (rowA >= N) rowA = N - 1;              // clamp; results discarded on store

    f32x4 acc[8] = {};
#pragma unroll
    for (int ks = 0; ks < 4; ++ks) {
        int k = ks * 32 + lr * 8;
        short8 a = *(const short8*)(hbf + (size_t)rowA * 128 + k);
#pragma unroll
        for (int t = 0; t < 8; ++t) {
            int o = t * 16 + lc;
            short8 b = *(const short8*)(W + o * 128 + k);
            acc[t] = __builtin_amdgcn_mfma_f32_16x16x32_bf16(a, b, acc[t], 0, 0, 0);
        }
    }
#pragma unroll
    for (int j = 0; j < 4; ++j) {
        int r = blockIdx.x * 64 + w * 16 + lr * 4 + j;
        if (r < N) {
#pragma unroll
            for (int t = 0; t < 8; ++t) {
                int c = t * 16 + lc;
                P[(size_t)r * 128 + c] = f2bf(acc[t][j]);
            }
        }
    }
}

// ---- kernel 2: out = e@W_eT + hu[src] + hw[tgt] (fused, 64 edges/block) ----
__global__ __launch_bounds__(256) void edge_kernel(
    const float* __restrict__ e,              // [E][64] fp32
    const int* __restrict__ srcIdx,           // [E]
    const int* __restrict__ tgtIdx,           // [E]
    const unsigned short* __restrict__ We,    // [128][64] bf16
    const unsigned short* __restrict__ hu,    // [N][128] bf16
    const unsigned short* __restrict__ hw,
    float* __restrict__ out) {                // [E][128] fp32
    __shared__ unsigned short sA[64][72];     // e tile bf16, padded stride
    __shared__ int sS[64], sT[64];

    int tid = threadIdx.x;
    size_t ebase = (size_t)blockIdx.x * 64;

    // stage e tile -> bf16 LDS (fully coalesced float4 reads)
    const float4* e4 = (const float4*)(e + ebase * 64);
#pragma unroll
    for (int i = 0; i < 4; ++i) {
        int idx4 = i * 256 + tid;             // 0..1023
        float4 v = e4[idx4];
        int fl = idx4 << 2;
        int row = fl >> 6, col = fl & 63;
        ushort4 o;
        o.x = f2bf(v.x); o.y = f2bf(v.y); o.z = f2bf(v.z); o.w = f2bf(v.w);
        *(ushort4*)&sA[row][col] = o;
    }
    if (tid < 64)       sS[tid]      = srcIdx[ebase + tid];
    else if (tid < 128) sT[tid - 64] = tgtIdx[ebase + tid - 64];
    __syncthreads();

    int w = tid >> 6, l = tid & 63;
    int lr = l >> 4, lc = l & 15;

    f32x4 acc[8] = {};
#pragma unroll
    for (int ks = 0; ks < 2; ++ks) {
        int k = ks * 32 + lr * 8;
        short8 a = *(const short8*)(&sA[w * 16 + lc][k]);
#pragma unroll
        for (int t = 0; t < 8; ++t) {
            int o = t * 16 + lc;
            short8 b = *(const short8*)(We + o * 64 + k);   // L1-resident 16KB
            acc[t] = __builtin_amdgcn_mfma_f32_16x16x32_bf16(a, b, acc[t], 0, 0, 0);
        }
    }

    // epilogue: gather hu[src], hw[tgt] (bf16) + add + fp32 store
#pragma unroll
    for (int j = 0; j < 4; ++j) {
        int r = w * 16 + lr * 4 + j;
        int s = sS[r], t2 = sT[r];
        const unsigned short* huR = hu + (size_t)s  * 128;
        const unsigned short* hwR = hw + (size_t)t2 * 128;
        float* oR = out + (ebase + r) * 128;
#pragma unroll
        for (int t = 0; t < 8; ++t) {
            int c = t * 16 + lc;
            oR[c] = acc[t][j] + bf2f(huR[c]) + bf2f(hwR[c]);
        }
    }
}

extern "C" void kernel_launch(void* const* d_in, const int* in_sizes, int n_in,
                              void* d_out, int out_size, void* d_ws, size_t ws_size,
                              hipStream_t stream) {
    const float* h   = (const float*)d_in[0];
    const float* e   = (const float*)d_in[1];
    const int*   ei  = (const int*)d_in[2];
    const float* We  = (const float*)d_in[3];
    const float* Whu = (const float*)d_in[4];
    const float* Whw = (const float*)d_in[5];
    float* out = (float*)d_out;

    int N = in_sizes[0] / IN_DIM;     // 50000
    int E = in_sizes[1] / EDGE_DIM;   // 800000
    const int* srcI = ei;
    const int* tgtI = ei + E;

    // workspace layout (bytes):
    //   [0)            h_bf16    N*128*2 = 12,800,000
    //   [+0]           W_e bf16  16384
    //   [+16384]       W_hu bf16 32768
    //   [+49152]       W_hw bf16 32768
    //   [+81920]       hu bf16   N*128*2
    //   [...]          hw bf16   N*128*2           total ~38.5 MB
    char* ws = (char*)d_ws;
    unsigned short* hbf  = (unsigned short*)ws;
    size_t offW = (size_t)N * IN_DIM * 2;
    unsigned short* wWe  = (unsigned short*)(ws + offW);
    unsigned short* wWhu = (unsigned short*)(ws + offW + 16384);
    unsigned short* wWhw = (unsigned short*)(ws + offW + 49152);
    unsigned short* hu   = (unsigned short*)(ws + offW + 81920);
    unsigned short* hw   = hu + (size_t)N * OUT_DIM;

    int n4h = N * IN_DIM / 4;
    cvt_h_kernel<<<(n4h + 255) / 256, 256, 0, stream>>>(h, hbf, n4h);
    cvt_w_kernel<<<160, 256, 0, stream>>>(We, Whu, Whw, wWe, wWhu, wWhw);

    dim3 g1((N + 63) / 64, 2);
    proj_kernel<<<g1, 256, 0, stream>>>(hbf, wWhu, wWhw, hu, hw, N);

    edge_kernel<<<E / 64, 256, 0, stream>>>(e, srcI, tgtI, wWe, hu, hw, out);
}